// Round 6
// baseline (1087.267 us; speedup 1.0000x reference)
//
#include <hip/hip_runtime.h>
#include <cstdint>

typedef int i32x4 __attribute__((ext_vector_type(4)));
typedef int i32x16 __attribute__((ext_vector_type(16)));

#define M_DIM 8192
#define N_DIM 11008
#define K_DIM 4096
#define NTILES 64            // K-tiles of BK=64
#define DEPTH 4              // LDS ring depth

// ws layout (bytes)
#define WS_AMAX_OFF   0                      // 1024 floats
#define WS_WSUM_OFF   4096                   // 1024 doubles
#define WS_SCALES_OFF 12288                  // 4 floats
#define WS_QX_OFF     16384                  // 8192*4096 int8
#define WS_TW_OFF     (16384 + 33554432)     // 11008*4096 int8

__device__ __forceinline__ void gload_lds16(const void* g, void* l) {
  __builtin_amdgcn_global_load_lds(
      (const __attribute__((address_space(1))) unsigned int*)g,
      (__attribute__((address_space(3))) unsigned int*)l, 16, 0, 0);
}

// ---------------- reductions ----------------

__global__ void reduce_amax(const float* __restrict__ x, float* __restrict__ partial, int n4) {
  const float4* xv = (const float4*)x;
  float m = 0.f;
  for (long i = (long)blockIdx.x * blockDim.x + threadIdx.x; i < n4;
       i += (long)gridDim.x * blockDim.x) {
    float4 v = xv[i];
    m = fmaxf(m, fmaxf(fmaxf(fabsf(v.x), fabsf(v.y)), fmaxf(fabsf(v.z), fabsf(v.w))));
  }
  __shared__ float sm[256];
  sm[threadIdx.x] = m;
  __syncthreads();
  for (int s = 128; s > 0; s >>= 1) {
    if (threadIdx.x < s) sm[threadIdx.x] = fmaxf(sm[threadIdx.x], sm[threadIdx.x + s]);
    __syncthreads();
  }
  if (threadIdx.x == 0) partial[blockIdx.x] = sm[0];
}

__global__ void reduce_wsum(const float* __restrict__ w, double* __restrict__ partial, int n4) {
  const float4* wv = (const float4*)w;
  double acc = 0.0;
  for (long i = (long)blockIdx.x * blockDim.x + threadIdx.x; i < n4;
       i += (long)gridDim.x * blockDim.x) {
    float4 v = wv[i];
    acc += (double)fabsf(v.x) + (double)fabsf(v.y) + (double)fabsf(v.z) + (double)fabsf(v.w);
  }
  __shared__ double sd[256];
  sd[threadIdx.x] = acc;
  __syncthreads();
  for (int s = 128; s > 0; s >>= 1) {
    if (threadIdx.x < s) sd[threadIdx.x] += sd[threadIdx.x + s];
    __syncthreads();
  }
  if (threadIdx.x == 0) partial[blockIdx.x] = sd[0];
}

__global__ void finalize_scales(const float* __restrict__ amax_p,
                                const double* __restrict__ wsum_p,
                                float* __restrict__ scales) {
  __shared__ float sm[1024];
  __shared__ double sd[1024];
  const int t = threadIdx.x;
  sm[t] = amax_p[t];
  sd[t] = wsum_p[t];
  __syncthreads();
  for (int s = 512; s > 0; s >>= 1) {
    if (t < s) {
      sm[t] = fmaxf(sm[t], sm[t + s]);
      sd[t] += sd[t + s];
    }
    __syncthreads();
  }
  if (t == 0) {
    float act_scale = fmaxf(sm[0] / 127.0f, 1e-8f);
    float w_scale = (float)(sd[0] / (double)((long long)N_DIM * K_DIM)) + 1e-8f;
    scales[0] = act_scale;
    scales[1] = w_scale;
    scales[2] = act_scale * w_scale;
  }
}

// ---------------- quantize ----------------

__device__ __forceinline__ int quant_clip(float v, float s, float lim) {
  float r = rintf(v / s);                 // round-half-even, matches jnp.round
  r = fminf(fmaxf(r, -lim), lim);
  return (int)r;
}

__global__ void quant_x(const float* __restrict__ x, const float* __restrict__ scales,
                        int8_t* __restrict__ q) {
  const float s = scales[0];
  const long i = (long)blockIdx.x * blockDim.x + threadIdx.x;  // 16 elems/thread
  const float4* xv = (const float4*)x + (i << 2);
  i32x4 pk;
#pragma unroll
  for (int j = 0; j < 4; ++j) {
    float4 v = xv[j];
    int b0 = quant_clip(v.x, s, 127.f);
    int b1 = quant_clip(v.y, s, 127.f);
    int b2 = quant_clip(v.z, s, 127.f);
    int b3 = quant_clip(v.w, s, 127.f);
    pk[j] = (b0 & 255) | ((b1 & 255) << 8) | ((b2 & 255) << 16) | (b3 << 24);
  }
  *((i32x4*)q + i) = pk;
}

__global__ void tern_w(const float* __restrict__ w, const float* __restrict__ scales,
                       int8_t* __restrict__ q) {
  const float s = scales[1];
  const long i = (long)blockIdx.x * blockDim.x + threadIdx.x;
  const float4* wv = (const float4*)w + (i << 2);
  i32x4 pk;
#pragma unroll
  for (int j = 0; j < 4; ++j) {
    float4 v = wv[j];
    int b0 = quant_clip(v.x, s, 1.f);
    int b1 = quant_clip(v.y, s, 1.f);
    int b2 = quant_clip(v.z, s, 1.f);
    int b3 = quant_clip(v.w, s, 1.f);
    pk[j] = (b0 & 255) | ((b1 & 255) << 8) | ((b2 & 255) << 16) | (b3 << 24);
  }
  *((i32x4*)q + i) = pk;
}

// ---------------- int8 GEMM: 256x256 tile, BK=64, depth-4 ring, PING-PONG waves ----------
// 8 waves (2m x 4n). SIMD i hosts waves i (G0) and i+4 (G1).
//   G0 (waves 0-3): read frags(t) -> MFMA(t)          [read-first]
//   G1 (waves 4-7): MFMA(t) on frags read last iter -> read frags(t+1)  [MFMA-first]
// => each SIMD always has one wave feeding the MFMA pipe while the other issues
// LDS reads: pipes overlap instead of running in series (int accumulation is
// order-independent -> bit-exact).
// Ring: tile t staged at iter t-3; per iter: vmcnt(4) BEFORE barrier guarantees
// tile t+1 staged by ALL waves at the barrier (outstanding = t+1(4)+t+2(4)=8,
// wait->4). stage(t+3) AFTER barrier overwrites slot (t-1)&3 whose last readers
// ran in epoch t-1 (barrier-separated). No lgkmcnt(0) in loop: all reads of a
// buffer are consumed by compiler-waited MFMAs >=1 barrier before overwrite.
// Tail: dummy re-stage of tile NT-1 into dead slots keeps vmcnt counts uniform.
// LDS layout (BK=64): byte(row,chunk) = (row>>1)*128 + (row&1)*64
//   + ((chunk ^ ((row>>1)&3))<<4); linear on the gload_lds write side.

__global__ __launch_bounds__(512, 2) void gemm_i8(const int8_t* __restrict__ qx,
                                                  const int8_t* __restrict__ tw,
                                                  const float* __restrict__ scales,
                                                  float* __restrict__ out) {
  __shared__ __align__(16) int8_t lds[DEPTH][32768];   // [d]: A 0..16K, B 16K..32K

  const int tid = threadIdx.x;
  const int l = tid & 63;
  const int w = tid >> 6;
  const int lane31 = l & 31;
  const int khalf = l >> 5;

  // ---- block -> tile mapping, 2D XCD chunk (bijective: 1376 = 8*172) ----
  const int bid = blockIdx.x;
  const int xcd = bid & 7;
  const int local = bid >> 3;               // 0..171
  const int ni = local >> 2;                // 0..42
  const int mi = (xcd << 2) + (local & 3);  // 0..31
  const long row0 = (long)mi << 8;
  const long col0 = (long)ni << 8;

  // ---- staging: wave w loads rows [32w,32w+32) of A and of B, 2 gloads each ----
  const int srow = ((l >> 3) << 1) + ((l >> 2) & 1);
  const int schk = ((l & 3) ^ ((l >> 3) & 3)) << 4;
  const int8_t* pA = qx + (row0 + 32 * w + srow) * (long)K_DIM + schk;
  const int8_t* pB = tw + (col0 + 32 * w + srow) * (long)K_DIM + schk;
  const int ldsA = w << 11;
  const int ldsB = 16384 + (w << 11);

  auto stage = [&](int d, int kt) {
    const long cb = (long)kt << 6;
    gload_lds16(pA + cb, lds[d] + ldsA);
    gload_lds16(pA + cb + 16 * (long)K_DIM, lds[d] + ldsA + 1024);
    gload_lds16(pB + cb, lds[d] + ldsB);
    gload_lds16(pB + cb + 16 * (long)K_DIM, lds[d] + ldsB + 1024);
  };

  // ---- read-side per-lane offsets ----
  const int rbl = ((lane31 >> 1) << 7) + ((lane31 & 1) << 6);
  const int x4 = (lane31 >> 1) & 3;
  int cOffR[4];
#pragma unroll
  for (int c = 0; c < 4; ++c) cOffR[c] = ((c ^ x4) << 4);
  const int aBase = ((w >> 2) << 13) + rbl;          // + mf*2048
  const int bBase = 16384 + ((w & 3) << 12) + rbl;   // + nf*2048

  i32x16 acc[4][2];
#pragma unroll
  for (int mf = 0; mf < 4; ++mf)
#pragma unroll
    for (int nf = 0; nf < 2; ++nf)
#pragma unroll
      for (int e = 0; e < 16; ++e) acc[mf][nf][e] = 0;

  // fragment registers (G1 holds these across the barrier)
  i32x4 fa0[4], fa1[4], fb0[2], fb1[2];

  auto read_frags = [&](const int8_t* buf) {
#pragma unroll
    for (int mf = 0; mf < 4; ++mf)
      fa0[mf] = *(const i32x4*)(buf + aBase + mf * 2048 + cOffR[khalf]);
#pragma unroll
    for (int nf = 0; nf < 2; ++nf)
      fb0[nf] = *(const i32x4*)(buf + bBase + nf * 2048 + cOffR[khalf]);
#pragma unroll
    for (int mf = 0; mf < 4; ++mf)
      fa1[mf] = *(const i32x4*)(buf + aBase + mf * 2048 + cOffR[2 + khalf]);
#pragma unroll
    for (int nf = 0; nf < 2; ++nf)
      fb1[nf] = *(const i32x4*)(buf + bBase + nf * 2048 + cOffR[2 + khalf]);
  };

  auto mfma_all = [&]() {
    __builtin_amdgcn_s_setprio(1);
#pragma unroll
    for (int mf = 0; mf < 4; ++mf) {
      acc[mf][0] = __builtin_amdgcn_mfma_i32_32x32x32_i8(fa0[mf], fb0[0], acc[mf][0], 0, 0, 0);
      acc[mf][1] = __builtin_amdgcn_mfma_i32_32x32x32_i8(fa0[mf], fb0[1], acc[mf][1], 0, 0, 0);
    }
#pragma unroll
    for (int mf = 0; mf < 4; ++mf) {
      acc[mf][0] = __builtin_amdgcn_mfma_i32_32x32x32_i8(fa1[mf], fb1[0], acc[mf][0], 0, 0, 0);
      acc[mf][1] = __builtin_amdgcn_mfma_i32_32x32x32_i8(fa1[mf], fb1[1], acc[mf][1], 0, 0, 0);
    }
    __builtin_amdgcn_s_setprio(0);
  };

  const bool g1 = (w >= 4);

  // ---- prologue: tiles 0,1,2 in flight ----
  stage(0, 0);
  stage(1, 1);
  stage(2, 2);

#pragma unroll 4
  for (int t = 0; t < NTILES; ++t) {
    asm volatile("s_waitcnt vmcnt(4)" ::: "memory");  // t+1 staged (all waves, pre-barrier)
    __builtin_amdgcn_s_barrier();
    asm volatile("" ::: "memory");

    const int kt3 = (t + 3 < NTILES) ? t + 3 : NTILES - 1;
    stage((t + 3) & 3, kt3);                          // overwrite slot (t-1)&3 (free)

    const int8_t* bufc = lds[t & 3];
    const int8_t* bufn = lds[(t + 1) & 3];

    if (!g1) {
      read_frags(bufc);       // G0: read-first
      mfma_all();
    } else {
      if (t == 0) read_frags(bufc);   // G1 catch-up on first iter
      mfma_all();                     // G1: MFMA-first (frags from last iter)
      if (t + 1 < NTILES) read_frags(bufn);
    }
  }

  // ---- epilogue: C/D 32x32 layout: col=lane&31, row=(reg&3)+8*(reg>>2)+4*(lane>>5) ----
  const float osc = scales[2];
  const int rbase = khalf << 2;
#pragma unroll
  for (int mf = 0; mf < 4; ++mf)
#pragma unroll
    for (int nf = 0; nf < 2; ++nf)
#pragma unroll
      for (int reg = 0; reg < 16; ++reg) {
        int rr = (w >> 2) * 128 + mf * 32 + rbase + (reg & 3) + ((reg >> 2) << 3);
        int cc = (w & 3) * 64 + nf * 32 + lane31;
        out[(row0 + rr) * (long)N_DIM + (col0 + cc)] = (float)acc[mf][nf][reg] * osc;
      }
}

// ---------------- launch ----------------

extern "C" void kernel_launch(void* const* d_in, const int* in_sizes, int n_in,
                              void* d_out, int out_size, void* d_ws, size_t ws_size,
                              hipStream_t stream) {
  const float* x = (const float*)d_in[0];   // [4,2048,4096]
  const float* W = (const float*)d_in[1];   // [11008,4096]
  float* out = (float*)d_out;               // [4,2048,11008]

  char* ws = (char*)d_ws;
  float*  amax_p = (float*)(ws + WS_AMAX_OFF);
  double* wsum_p = (double*)(ws + WS_WSUM_OFF);
  float*  scales = (float*)(ws + WS_SCALES_OFF);
  int8_t* qx = (int8_t*)(ws + WS_QX_OFF);
  int8_t* tw = (int8_t*)(ws + WS_TW_OFF);

  reduce_amax<<<1024, 256, 0, stream>>>(x, amax_p, (M_DIM * (long)K_DIM) / 4);
  reduce_wsum<<<1024, 256, 0, stream>>>(W, wsum_p, (N_DIM * (long)K_DIM) / 4);
  finalize_scales<<<1, 1024, 0, stream>>>(amax_p, wsum_p, scales);
  quant_x<<<(M_DIM * (long)K_DIM) / 16 / 256, 256, 0, stream>>>(x, scales, qx);
  tern_w<<<(N_DIM * (long)K_DIM) / 16 / 256, 256, 0, stream>>>(W, scales, tw);

  const int grid = (M_DIM / 256) * (N_DIM / 256);   // 32*43 = 1376 = 8*172
  gemm_i8<<<grid, 512, 0, stream>>>(qx, tw, scales, out);
}

// Round 9
// 549.315 us; speedup vs baseline: 1.9793x; 1.9793x over previous
//
#include <hip/hip_runtime.h>
#include <cstdint>

typedef int i32x4 __attribute__((ext_vector_type(4)));
typedef int i32x16 __attribute__((ext_vector_type(16)));

#define M_DIM 8192
#define N_DIM 11008
#define K_DIM 4096
#define K32   (K_DIM / 32)   // 128 k32-fragments per row-block
#define NTILES 64            // K-tiles of BK=64 (2 k32 each)

// ws layout (bytes)
#define WS_AMAX_OFF   0                      // 1024 floats
#define WS_WSUM_OFF   4096                   // 1024 doubles
#define WS_SCALES_OFF 12288                  // 4 floats
#define WS_QX_OFF     16384                  // 8192*4096 int8 (fragment-major)
#define WS_TW_OFF     (16384 + 33554432)     // 11008*4096 int8 (fragment-major)

__device__ __forceinline__ void gload_lds16(const void* g, void* l) {
  __builtin_amdgcn_global_load_lds(
      (const __attribute__((address_space(1))) unsigned int*)g,
      (__attribute__((address_space(3))) unsigned int*)l, 16, 0, 0);
}

// ---------------- reductions ----------------

__global__ void reduce_amax(const float* __restrict__ x, float* __restrict__ partial, int n4) {
  const float4* xv = (const float4*)x;
  float m = 0.f;
  for (long i = (long)blockIdx.x * blockDim.x + threadIdx.x; i < n4;
       i += (long)gridDim.x * blockDim.x) {
    float4 v = xv[i];
    m = fmaxf(m, fmaxf(fmaxf(fabsf(v.x), fabsf(v.y)), fmaxf(fabsf(v.z), fabsf(v.w))));
  }
  __shared__ float sm[256];
  sm[threadIdx.x] = m;
  __syncthreads();
  for (int s = 128; s > 0; s >>= 1) {
    if (threadIdx.x < s) sm[threadIdx.x] = fmaxf(sm[threadIdx.x], sm[threadIdx.x + s]);
    __syncthreads();
  }
  if (threadIdx.x == 0) partial[blockIdx.x] = sm[0];
}

__global__ void reduce_wsum(const float* __restrict__ w, double* __restrict__ partial, int n4) {
  const float4* wv = (const float4*)w;
  double acc = 0.0;
  for (long i = (long)blockIdx.x * blockDim.x + threadIdx.x; i < n4;
       i += (long)gridDim.x * blockDim.x) {
    float4 v = wv[i];
    acc += (double)fabsf(v.x) + (double)fabsf(v.y) + (double)fabsf(v.z) + (double)fabsf(v.w);
  }
  __shared__ double sd[256];
  sd[threadIdx.x] = acc;
  __syncthreads();
  for (int s = 128; s > 0; s >>= 1) {
    if (threadIdx.x < s) sd[threadIdx.x] += sd[threadIdx.x + s];
    __syncthreads();
  }
  if (threadIdx.x == 0) partial[blockIdx.x] = sd[0];
}

__global__ void finalize_scales(const float* __restrict__ amax_p,
                                const double* __restrict__ wsum_p,
                                float* __restrict__ scales) {
  __shared__ float sm[1024];
  __shared__ double sd[1024];
  const int t = threadIdx.x;
  sm[t] = amax_p[t];
  sd[t] = wsum_p[t];
  __syncthreads();
  for (int s = 512; s > 0; s >>= 1) {
    if (t < s) {
      sm[t] = fmaxf(sm[t], sm[t + s]);
      sd[t] += sd[t + s];
    }
    __syncthreads();
  }
  if (t == 0) {
    float act_scale = fmaxf(sm[0] / 127.0f, 1e-8f);
    float w_scale = (float)(sd[0] / (double)((long long)N_DIM * K_DIM)) + 1e-8f;
    scales[0] = act_scale;
    scales[1] = w_scale;
    scales[2] = act_scale * w_scale;
  }
}

// ---------------- quantize + fragment-major pack ----------------
// Layout: qp[r32][k32][lane64][16B]; lane l byte b = elem(row r32*32 + (l&31),
//   k = k32*32 + (l>>5)*16 + b)  — exactly the mfma_i32_32x32x32_i8 A/B operand
//   (same lane mapping the row-major LDS reads of passing rounds r1-r5 used).

__device__ __forceinline__ int quant_clip(float v, float s, float lim) {
  float r = rintf(v / s);                 // round-half-even, matches jnp.round
  r = fminf(fmaxf(r, -lim), lim);
  return (int)r;
}

template <int LIM_IS_W>
__global__ void quant_pack(const float* __restrict__ src, const float* __restrict__ scales,
                           int8_t* __restrict__ qp) {
  __shared__ __align__(16) int8_t buf[32 * 144];   // 32 rows x 128B, stride 144
  const float s = scales[LIM_IS_W ? 1 : 0];
  const float lim = LIM_IS_W ? 1.f : 127.f;
  const int br = blockIdx.x >> 5;          // row-block (32 rows)
  const int bk = blockIdx.x & 31;          // k-block (128 cols)
  const int t = threadIdx.x;

  // phase 1: quantize 32x128 into LDS
  const int row = t >> 3, kc = (t & 7) << 4;
  const float4* sp = (const float4*)(src + ((long)(br * 32 + row)) * K_DIM + bk * 128 + kc);
  i32x4 pk;
#pragma unroll
  for (int j = 0; j < 4; ++j) {
    float4 v = sp[j];
    int b0 = quant_clip(v.x, s, lim);
    int b1 = quant_clip(v.y, s, lim);
    int b2 = quant_clip(v.z, s, lim);
    int b3 = quant_clip(v.w, s, lim);
    pk[j] = (b0 & 255) | ((b1 & 255) << 8) | ((b2 & 255) << 16) | (b3 << 24);
  }
  *(i32x4*)(buf + row * 144 + kc) = pk;
  __syncthreads();

  // phase 2: emit 4 fragments (1KB each), coalesced
  const int g = t >> 6, l = t & 63;
  i32x4 fr = *(const i32x4*)(buf + (l & 31) * 144 + g * 32 + ((l >> 5) << 4));
  *((i32x4*)(qp + ((long)br * K32 + bk * 4 + g) * 1024) + l) = fr;
}

// ---------------- int8 GEMM: 256x256 tile, BK=64, B-in-regs (plain loads) ----------------
// 8 waves (2m x 4n), per-wave 128x64 = acc[4][2] of 32x32 i32 frags, 16 MFMA/tile.
// NO inline asm anywhere (r7/r8 lesson: asm loads' dest regs are written async;
// compiler copies/spills of pending asm outputs = silent corruption/faults).
// A: fragment-major qxp -> gload_lds (wave-uniform dest, 1KB linear frags),
//    double-buffered 2x16KB LDS. B: fragment-major twp -> plain i32x4 loads to
//    regs 1 tile ahead (compiler inserts correct counted vmcnt, spill-safe).
// Per tile: stageA(nxt,t+1); loadB(bnext,t+1); 8 lane-linear ds_read_b128 (cur);
//   16 MFMA; __syncthreads() [drains vmcnt/lgkm: stage+loadB issued a full tile
//   earlier -> near-free; barrier frees cur for next overwrite].

__global__ __launch_bounds__(512, 2) void gemm_i8(const int8_t* __restrict__ qxp,
                                                  const int8_t* __restrict__ twp,
                                                  const float* __restrict__ scales,
                                                  float* __restrict__ out) {
  __shared__ __align__(16) int8_t lds[2][16384];

  const int tid = threadIdx.x;
  const int l = tid & 63;
  const int w = tid >> 6;
  const int lane31 = l & 31;
  const int khalf = l >> 5;

  // ---- block -> tile mapping, 2D XCD chunk (bijective: 1376 = 8*172) ----
  const int bid = blockIdx.x;
  const int xcd = bid & 7;
  const int local = bid >> 3;               // 0..171
  const int ni = local >> 2;                // 0..42
  const int mi = (xcd << 2) + (local & 3);  // 0..31
  const long row0 = (long)mi << 8;
  const long col0 = (long)ni << 8;

  // ---- A staging: wave w stages r32 = mi*8+w (per-lane global src, uniform LDS dest) ----
  const int8_t* aSrc = qxp + ((long)(mi * 8 + w) * K32) * 1024 + l * 16;
  auto stageA = [&](int slot, int kt) {
    gload_lds16(aSrc + (long)(2 * kt) * 1024, &lds[slot][w * 2048]);
    gload_lds16(aSrc + (long)(2 * kt + 1) * 1024, &lds[slot][w * 2048 + 1024]);
  };

  // ---- B plain loads: wave w covers n32 = ni*8 + (w&3)*2 + {0,1} ----
  const int8_t* bSrc0 = twp + ((long)(ni * 8 + (w & 3) * 2) * K32) * 1024 + l * 16;
  const int8_t* bSrc1 = bSrc0 + (long)K32 * 1024;
  auto loadB = [&](i32x4 (&dst)[4], int kt) {          // dst[nf*2+sl]
    const long o = (long)(2 * kt) * 1024;
    dst[0] = *(const i32x4*)(bSrc0 + o);
    dst[1] = *(const i32x4*)(bSrc0 + o + 1024);
    dst[2] = *(const i32x4*)(bSrc1 + o);
    dst[3] = *(const i32x4*)(bSrc1 + o + 1024);
  };

  const int aRd = ((w >> 2) * 8) * 1024 + l * 16;      // + (mf*2+sl)*1024

  i32x16 acc[4][2];
#pragma unroll
  for (int mf = 0; mf < 4; ++mf)
#pragma unroll
    for (int nf = 0; nf < 2; ++nf)
#pragma unroll
      for (int e = 0; e < 16; ++e) acc[mf][nf][e] = 0;

  auto body = [&](int t, i32x4 (&bcur)[4], i32x4 (&bnext)[4]) {
    const int cur = t & 1;
    const int ktn = (t + 1 < NTILES) ? t + 1 : NTILES - 1;
    stageA(cur ^ 1, ktn);                  // into the buffer freed by last barrier
    loadB(bnext, ktn);                     // harmless re-load at the tail
    const int8_t* buf = lds[cur];
    i32x4 af[4][2];
#pragma unroll
    for (int mf = 0; mf < 4; ++mf)
#pragma unroll
      for (int sl = 0; sl < 2; ++sl)
        af[mf][sl] = *(const i32x4*)(buf + aRd + (mf * 2 + sl) * 1024);
    __builtin_amdgcn_s_setprio(1);
#pragma unroll
    for (int mf = 0; mf < 4; ++mf) {
      acc[mf][0] = __builtin_amdgcn_mfma_i32_32x32x32_i8(af[mf][0], bcur[0], acc[mf][0], 0, 0, 0);
      acc[mf][1] = __builtin_amdgcn_mfma_i32_32x32x32_i8(af[mf][0], bcur[2], acc[mf][1], 0, 0, 0);
      acc[mf][0] = __builtin_amdgcn_mfma_i32_32x32x32_i8(af[mf][1], bcur[1], acc[mf][0], 0, 0, 0);
      acc[mf][1] = __builtin_amdgcn_mfma_i32_32x32x32_i8(af[mf][1], bcur[3], acc[mf][1], 0, 0, 0);
    }
    __builtin_amdgcn_s_setprio(0);
    __syncthreads();                        // drains stage/loads; frees cur
  };

  // ---- prologue: tile 0 staged + B(0) loaded, fully drained ----
  i32x4 bEv[4], bOd[4];
  stageA(0, 0);
  loadB(bEv, 0);
  __syncthreads();

  for (int tp = 0; tp < NTILES / 2; ++tp) {
    body(2 * tp, bEv, bOd);
    body(2 * tp + 1, bOd, bEv);
  }

  // ---- epilogue: C/D 32x32 layout: col=lane&31, row=(reg&3)+8*(reg>>2)+4*(lane>>5) ----
  const float osc = scales[2];
  const int rbase = khalf << 2;
#pragma unroll
  for (int mf = 0; mf < 4; ++mf)
#pragma unroll
    for (int nf = 0; nf < 2; ++nf)
#pragma unroll
      for (int reg = 0; reg < 16; ++reg) {
        int rr = (w >> 2) * 128 + mf * 32 + rbase + (reg & 3) + ((reg >> 2) << 3);
        int cc = (w & 3) * 64 + nf * 32 + lane31;
        out[(row0 + rr) * (long)N_DIM + (col0 + cc)] = (float)acc[mf][nf][reg] * osc;
      }
}

// ---------------- launch ----------------

extern "C" void kernel_launch(void* const* d_in, const int* in_sizes, int n_in,
                              void* d_out, int out_size, void* d_ws, size_t ws_size,
                              hipStream_t stream) {
  const float* x = (const float*)d_in[0];   // [4,2048,4096]
  const float* W = (const float*)d_in[1];   // [11008,4096]
  float* out = (float*)d_out;               // [4,2048,11008]

  char* ws = (char*)d_ws;
  float*  amax_p = (float*)(ws + WS_AMAX_OFF);
  double* wsum_p = (double*)(ws + WS_WSUM_OFF);
  float*  scales = (float*)(ws + WS_SCALES_OFF);
  int8_t* qxp = (int8_t*)(ws + WS_QX_OFF);
  int8_t* twp = (int8_t*)(ws + WS_TW_OFF);

  reduce_amax<<<1024, 256, 0, stream>>>(x, amax_p, (M_DIM * (long)K_DIM) / 4);
  reduce_wsum<<<1024, 256, 0, stream>>>(W, wsum_p, (N_DIM * (long)K_DIM) / 4);
  finalize_scales<<<1, 1024, 0, stream>>>(amax_p, wsum_p, scales);
  quant_pack<0><<<(M_DIM / 32) * 32, 256, 0, stream>>>(x, scales, qxp);
  quant_pack<1><<<(N_DIM / 32) * 32, 256, 0, stream>>>(W, scales, twp);

  const int grid = (M_DIM / 256) * (N_DIM / 256);   // 32*43 = 1376 = 8*172
  gemm_i8<<<grid, 512, 0, stream>>>(qxp, twp, scales, out);
}